// Round 8
// baseline (64.044 us; speedup 1.0000x reference)
//
#include <hip/hip_runtime.h>
#include <hip/hip_bf16.h>

// Problem constants
#define B_   2
#define T_   2
#define H_   56
#define W_   56
#define C_   256
#define NH_  8
#define HD_  32
#define NWW_ 14          // windows along W (W_sp=4)
#define WC_  (W_ * C_)   // 14336
#define P1_  (H_ * W_ * C_) // 802816 (one (b,t) plane)
#define TQ_  448         // queries per window = T*56*4
#define VIRT_ 336.0f     // zero-logit pooled tokens folded analytically (896-560)
#define MEXP_ 16.0f      // fixed softmax max (exp2 domain); realized |logit*log2e| < ~10

typedef __bf16 bf16;
typedef __bf16 bf16x8 __attribute__((ext_vector_type(8)));
typedef __bf16 bf16x4 __attribute__((ext_vector_type(4)));
typedef float  f32x4  __attribute__((ext_vector_type(4)));
typedef short  s16x4  __attribute__((ext_vector_type(4)));
typedef unsigned int  uint;
typedef uint   uint4v __attribute__((ext_vector_type(4)));
typedef uint   uint2v __attribute__((ext_vector_type(2)));
typedef unsigned short u16;

__device__ __forceinline__ uint pack2(float a, float b) {
    u16 ha = __builtin_bit_cast(u16, (bf16)a);
    u16 hb = __builtin_bit_cast(u16, (bf16)b);
    return (uint)ha | ((uint)hb << 16);
}

// 8 consecutive f32 -> bf16x8 (K/Q fragment)
__device__ __forceinline__ bf16x8 pack8(const float* __restrict__ p) {
    const f32x4 a = *(const f32x4*)p;
    const f32x4 b = *(const f32x4*)(p + 4);
    const uint4v u = {pack2(a[0], a[1]), pack2(a[2], a[3]),
                      pack2(b[0], b[1]), pack2(b[2], b[3])};
    return __builtin_bit_cast(bf16x8, u);
}

__device__ __forceinline__ s16x4 pack4(float a, float b, float c, float d) {
    const uint2v u = {pack2(a, b), pack2(c, d)};
    return __builtin_bit_cast(s16x4, u);
}

// ---------------------------------------------------------------------------
// Pre-kernel, 1024 threads.
// Blocks 0..55: pool (b,t,j) -> FINAL pm_k/pm_v (quarters reduced in LDS).
// Blocks 56..447: LePE depthwise 3x3 within 56x4 strips (bt, h-quad, strip-pair).
// ---------------------------------------------------------------------------
__launch_bounds__(1024, 1)
__global__ void pre_kernel(const float* __restrict__ k_in, const float* __restrict__ v_in,
                           const float* __restrict__ pool_w, const float* __restrict__ pool_b,
                           const float* __restrict__ gw, const float* __restrict__ gb,
                           float* __restrict__ pm_k, float* __restrict__ pm_v,
                           bf16* __restrict__ lepe) {
    const int bid = blockIdx.x;
    const int tid = threadIdx.x;

    if (bid < 56) {
        // ---- pool: (b,t,j); threads = (quarter 0..3, c 0..255) ----
        __shared__ float pws[4][224];
        __shared__ float red[3][4][2][256];
        const int j = bid % NWW_;
        const int t = (bid / NWW_) % T_;
        const int b = bid / (NWW_ * T_);
        const int quarter = tid >> 8;
        const int c = tid & 255;

        if (tid < 896) pws[tid / 224][tid % 224] = pool_w[tid];
        __syncthreads();

        float ak[4] = {0.f, 0.f, 0.f, 0.f};
        float av[4] = {0.f, 0.f, 0.f, 0.f};
        const int n0 = quarter * 56;
        #pragma unroll 4
        for (int i = 0; i < 56; ++i) {
            const int n = n0 + i;
            const int h = n >> 2, wi = n & 3;
            const size_t off = (size_t)(b * T_ + t) * P1_ + h * WC_ + (j * 4 + wi) * C_ + c;
            const float kv = k_in[off];
            const float vv = v_in[off];
            #pragma unroll
            for (int s = 0; s < 4; ++s) {
                ak[s] += kv * pws[s][n];
                av[s] += vv * pws[s][n];
            }
        }
        if (quarter > 0) {
            #pragma unroll
            for (int s = 0; s < 4; ++s) {
                red[quarter - 1][s][0][c] = ak[s];
                red[quarter - 1][s][1][c] = av[s];
            }
        }
        __syncthreads();
        if (quarter == 0) {
            #pragma unroll
            for (int s = 0; s < 4; ++s) {
                const float bias = pool_b[s];
                const float sk = ak[s] + red[0][s][0][c] + red[1][s][0][c] + red[2][s][0][c] + bias;
                const float sv = av[s] + red[0][s][1][c] + red[1][s][1][c] + red[2][s][1][c] + bias;
                const size_t o = ((size_t)(((b * T_ + t) * 4 + s) * NWW_ + j)) * C_ + c;
                pm_k[o] = sk;
                pm_v[o] = sv;
            }
        }
    } else {
        // ---- LePE: (bt, hq, strip-pair); threads = (hsub 0..3, c 0..255) ----
        const int r  = bid - 56;
        const int sp = r % 7;
        const int hq = (r / 7) % NWW_;
        const int bt = r / (7 * NWW_);
        const int h  = hq * 4 + (tid >> 8);
        const int c  = tid & 255;

        float wv9[9];
        #pragma unroll
        for (int k = 0; k < 9; ++k) wv9[k] = gw[c * 9 + k];
        const float bias = gb[c];

        #pragma unroll
        for (int s2 = 0; s2 < 2; ++s2) {
            const int strip = sp * 2 + s2;
            float tile[3][4];
            #pragma unroll
            for (int dy = 0; dy < 3; ++dy) {
                const int hh = h - 1 + dy;
                const bool ok = (hh >= 0 && hh < H_);
                #pragma unroll
                for (int x = 0; x < 4; ++x) {
                    tile[dy][x] = ok
                        ? v_in[(size_t)bt * P1_ + hh * WC_ + (strip * 4 + x) * C_ + c]
                        : 0.f;
                }
            }
            #pragma unroll
            for (int wi = 0; wi < 4; ++wi) {
                float acc = bias;
                #pragma unroll
                for (int dy = 0; dy < 3; ++dy) {
                    #pragma unroll
                    for (int dx = -1; dx <= 1; ++dx) {
                        const int xx = wi + dx;
                        if (xx >= 0 && xx < 4)
                            acc += wv9[dy * 3 + dx + 1] * tile[dy][xx];
                    }
                }
                lepe[(size_t)bt * P1_ + h * WC_ + (strip * 4 + wi) * C_ + c] = (bf16)acc;
            }
        }
    }
}

// ---------------------------------------------------------------------------
// Streaming attention: NO LDS, NO barriers. 3136 independent waves; each wave
// owns 2 q-tiles (16 rows) of one (window, head) and streams K/V fragments
// straight from global (L2/L3) into MFMA operands. Fixed-max softmax (exp2
// domain), lane-local PV via 16x16x16 B-operand trick, 336 virtual zero-logit
// tokens folded into the denominator. grid = 784 blocks x 256 threads.
// ---------------------------------------------------------------------------
__launch_bounds__(256, 4)
__global__ void attn_kernel(const float* __restrict__ q_in, const float* __restrict__ k_in,
                            const float* __restrict__ v_in, const float* __restrict__ pm_k,
                            const float* __restrict__ pm_v, const bf16* __restrict__ lepe,
                            float* __restrict__ out) {
    const int tid  = threadIdx.x;
    const int lane = tid & 63;
    const int wvid = (blockIdx.x << 2) + (tid >> 6);   // 0..3135
    const int wpair = wvid % 14;                       // q-tile group
    const int hw   = wvid / 14;                        // (window, head) 0..223
    const int nh   = hw & 7;
    const int nwi  = hw >> 3;
    const int b    = nwi / NWW_;
    const int ww   = nwi % NWW_;
    const int l15  = lane & 15;
    const int g    = lane >> 4;
    const int cbase = nh * 32;
    const float QS = 0.17677669529663687f * 1.4426950408889634f; // HD^-0.5 * log2(e)

    // ---- Q fragments (2 tiles: wpair, wpair+14), scaled into exp2 domain ----
    bf16x8 qf[2];
    #pragma unroll
    for (int ti = 0; ti < 2; ++ti) {
        const int qrow = (wpair + ti * 14) * 16 + l15;
        const int t = qrow / 224, r = qrow % 224;
        const int h = r >> 2, wi = r & 3;
        const size_t off = (size_t)(b * T_ + t) * P1_ + h * WC_ + (ww * 4 + wi) * C_ + cbase + g * 8;
        const f32x4 a0 = *(const f32x4*)(q_in + off);
        const f32x4 a1 = *(const f32x4*)(q_in + off + 4);
        const uint4v qp = {pack2(a0[0] * QS, a0[1] * QS), pack2(a0[2] * QS, a0[3] * QS),
                           pack2(a1[0] * QS, a1[1] * QS), pack2(a1[2] * QS, a1[3] * QS)};
        qf[ti] = __builtin_bit_cast(bf16x8, qp);
    }

    f32x4 o[2][2];
    float ssum[2];
    const f32x4 zf = {0.f, 0.f, 0.f, 0.f};
    #pragma unroll
    for (int ti = 0; ti < 2; ++ti) { o[ti][0] = zf; o[ti][1] = zf; ssum[ti] = 0.f; }

    auto computeFull = [&](const bf16x8& KA, const bf16x8& KB, const s16x4& V00,
                           const s16x4& V01, const s16x4& V10, const s16x4& V11) {
        #pragma unroll
        for (int ti = 0; ti < 2; ++ti) {
            const f32x4 s0 = __builtin_amdgcn_mfma_f32_16x16x32_bf16(KA, qf[ti], zf, 0, 0, 0);
            const f32x4 s1 = __builtin_amdgcn_mfma_f32_16x16x32_bf16(KB, qf[ti], zf, 0, 0, 0);
            const float p0 = __builtin_amdgcn_exp2f(s0[0] - MEXP_);
            const float p1 = __builtin_amdgcn_exp2f(s0[1] - MEXP_);
            const float p2 = __builtin_amdgcn_exp2f(s0[2] - MEXP_);
            const float p3 = __builtin_amdgcn_exp2f(s0[3] - MEXP_);
            const float p4 = __builtin_amdgcn_exp2f(s1[0] - MEXP_);
            const float p5 = __builtin_amdgcn_exp2f(s1[1] - MEXP_);
            const float p6 = __builtin_amdgcn_exp2f(s1[2] - MEXP_);
            const float p7 = __builtin_amdgcn_exp2f(s1[3] - MEXP_);
            ssum[ti] += ((p0 + p1) + (p2 + p3)) + ((p4 + p5) + (p6 + p7));
            const s16x4 pb0 = pack4(p0, p1, p2, p3);
            const s16x4 pb1 = pack4(p4, p5, p6, p7);
            o[ti][0] = __builtin_amdgcn_mfma_f32_16x16x16bf16_1k(V00, pb0, o[ti][0], 0, 0, 0);
            o[ti][0] = __builtin_amdgcn_mfma_f32_16x16x16bf16_1k(V01, pb1, o[ti][0], 0, 0, 0);
            o[ti][1] = __builtin_amdgcn_mfma_f32_16x16x16bf16_1k(V10, pb0, o[ti][1], 0, 0, 0);
            o[ti][1] = __builtin_amdgcn_mfma_f32_16x16x16bf16_1k(V11, pb1, o[ti][1], 0, 0, 0);
        }
    };
    auto computeHalf = [&](const bf16x8& KA, const s16x4& V00, const s16x4& V10) {
        #pragma unroll
        for (int ti = 0; ti < 2; ++ti) {
            const f32x4 s0 = __builtin_amdgcn_mfma_f32_16x16x32_bf16(KA, qf[ti], zf, 0, 0, 0);
            const float p0 = __builtin_amdgcn_exp2f(s0[0] - MEXP_);
            const float p1 = __builtin_amdgcn_exp2f(s0[1] - MEXP_);
            const float p2 = __builtin_amdgcn_exp2f(s0[2] - MEXP_);
            const float p3 = __builtin_amdgcn_exp2f(s0[3] - MEXP_);
            ssum[ti] += (p0 + p1) + (p2 + p3);
            const s16x4 pb0 = pack4(p0, p1, p2, p3);
            o[ti][0] = __builtin_amdgcn_mfma_f32_16x16x16bf16_1k(V00, pb0, o[ti][0], 0, 0, 0);
            o[ti][1] = __builtin_amdgcn_mfma_f32_16x16x16bf16_1k(V10, pb0, o[ti][1], 0, 0, 0);
        }
    };

    // lane-invariant offsets
    // K A-frag (s0): lane l15 = token tk, reads hd g*8..g*8+7; s1: tokens +16 (= +4 rows)
    const int koffA = (l15 >> 2) * WC_ + (l15 & 3) * C_ + cbase + g * 8;
    // V A-frag: lane (l15,g): hd = l15 (+16), tokens g*4+e -> row g, col e
    const int voffA = g * WC_ + cbase + l15;

    // ---- window chunks: 14 chunks of 32 tokens (8 h-rows each) ----
    for (int t = 0; t < 2; ++t) {
        const float* kb_ = k_in + (size_t)(b * T_ + t) * P1_ + ww * 4 * C_;
        const float* vb_ = v_in + (size_t)(b * T_ + t) * P1_ + ww * 4 * C_;
        #pragma unroll 1
        for (int rc = 0; rc < 7; ++rc) {
            const int cb = rc * 8 * WC_;
            const bf16x8 ka = pack8(kb_ + cb + koffA);
            const bf16x8 kb2 = pack8(kb_ + cb + koffA + 4 * WC_);
            const float* vp = vb_ + cb + voffA;
            const s16x4 v00 = pack4(vp[0], vp[C_], vp[2 * C_], vp[3 * C_]);
            const s16x4 v01 = pack4(vp[4 * WC_], vp[4 * WC_ + C_],
                                    vp[4 * WC_ + 2 * C_], vp[4 * WC_ + 3 * C_]);
            const s16x4 v10 = pack4(vp[16], vp[C_ + 16], vp[2 * C_ + 16], vp[3 * C_ + 16]);
            const s16x4 v11 = pack4(vp[4 * WC_ + 16], vp[4 * WC_ + C_ + 16],
                                    vp[4 * WC_ + 2 * C_ + 16], vp[4 * WC_ + 3 * C_ + 16]);
            computeFull(ka, kb2, v00, v01, v10, v11);
        }
    }

    // ---- pooled chunks: tokens 448..559 (112 real); chunk 3 is a half ----
    #pragma unroll 1
    for (int pc = 0; pc < 4; ++pc) {
        // K s0 tile: token i = pc*32 + l15
        const int i0 = pc * 32 + l15;
        const int t0 = i0 / 56, r0 = i0 - 56 * t0;
        const int sx0 = r0 / 14, j0 = r0 - 14 * sx0;
        const bf16x8 ka = pack8(pm_k + (size_t)(((b * T_ + t0) * 4 + sx0) * NWW_ + j0) * C_
                                     + cbase + g * 8);
        // V s0 tokens: i = pc*32 + g*4 + e
        float f0[4], fh0[4];
        #pragma unroll
        for (int e = 0; e < 4; ++e) {
            const int iv = pc * 32 + g * 4 + e;
            const int tv = iv / 56, rv = iv - 56 * tv;
            const int sv = rv / 14, jv = rv - 14 * sv;
            const float* pv = pm_v + (size_t)(((b * T_ + tv) * 4 + sv) * NWW_ + jv) * C_
                                   + cbase + l15;
            f0[e] = pv[0]; fh0[e] = pv[16];
        }
        const s16x4 v00 = pack4(f0[0], f0[1], f0[2], f0[3]);
        const s16x4 v10 = pack4(fh0[0], fh0[1], fh0[2], fh0[3]);

        if (pc < 3) {
            const int i1 = i0 + 16;
            const int t1 = i1 / 56, r1 = i1 - 56 * t1;
            const int sx1 = r1 / 14, j1 = r1 - 14 * sx1;
            const bf16x8 kb2 = pack8(pm_k + (size_t)(((b * T_ + t1) * 4 + sx1) * NWW_ + j1) * C_
                                          + cbase + g * 8);
            float f1[4], fh1[4];
            #pragma unroll
            for (int e = 0; e < 4; ++e) {
                const int iv = pc * 32 + 16 + g * 4 + e;
                const int tv = iv / 56, rv = iv - 56 * tv;
                const int sv = rv / 14, jv = rv - 14 * sv;
                const float* pv = pm_v + (size_t)(((b * T_ + tv) * 4 + sv) * NWW_ + jv) * C_
                                       + cbase + l15;
                f1[e] = pv[0]; fh1[e] = pv[16];
            }
            const s16x4 v01 = pack4(f1[0], f1[1], f1[2], f1[3]);
            const s16x4 v11 = pack4(fh1[0], fh1[1], fh1[2], fh1[3]);
            computeFull(ka, kb2, v00, v01, v10, v11);
        } else {
            computeHalf(ka, v00, v10);
        }
    }

    // ---- epilogue: denominator reduce, virtual zeros, LePE, store ----
    #pragma unroll
    for (int ti = 0; ti < 2; ++ti) {
        float den = ssum[ti];
        den += __shfl_xor(den, 16);
        den += __shfl_xor(den, 32);
        den += VIRT_ * 0.0000152587890625f; // 336 * 2^-16
        const float osc = 1.0f / den;       // valid in every lane, for q = l15

        // o[ti][h2] reg r = O[q=l15][cbase + h2*16 + g*4 + r] — fully lane-local
        const int qrow = (wpair + ti * 14) * 16 + l15;
        const int t = qrow / 224, rr = qrow % 224;
        const int h = rr >> 2, wi = rr & 3;
        const size_t off = (size_t)(b * T_ + t) * P1_ + h * WC_ + (ww * 4 + wi) * C_ + cbase;
        #pragma unroll
        for (int h2 = 0; h2 < 2; ++h2) {
            const int co = h2 * 16 + g * 4;
            const bf16x4 lp = *(const bf16x4*)(lepe + off + co);
            f32x4 val;
            #pragma unroll
            for (int r = 0; r < 4; ++r) val[r] = o[ti][h2][r] * osc + (float)lp[r];
            *(f32x4*)(out + off + co) = val;
        }
    }
}

// ---------------------------------------------------------------------------
extern "C" void kernel_launch(void* const* d_in, const int* in_sizes, int n_in,
                              void* d_out, int out_size, void* d_ws, size_t ws_size,
                              hipStream_t stream) {
    const float* qkv = (const float*)d_in[0];
    const float* gw  = (const float*)d_in[1];
    const float* gb  = (const float*)d_in[2];
    const float* pw  = (const float*)d_in[3];
    const float* pb  = (const float*)d_in[4];

    const size_t plane = (size_t)B_ * T_ * H_ * W_ * C_; // 3,211,264
    const float* q_in = qkv;
    const float* k_in = qkv + plane;
    const float* v_in = qkv + 2 * plane;

    const size_t pm_elems = (size_t)B_ * T_ * 4 * NWW_ * C_; // 57,344
    float* pm_k = (float*)d_ws;
    float* pm_v = pm_k + pm_elems;
    bf16*  lepe = (bf16*)(pm_v + pm_elems);
    float* outp = (float*)d_out;

    hipLaunchKernelGGL(pre_kernel, dim3(56 + 392), dim3(1024), 0, stream,
                       k_in, v_in, pw, pb, gw, gb, pm_k, pm_v, lepe);
    hipLaunchKernelGGL(attn_kernel, dim3(784), dim3(256), 0, stream,
                       q_in, k_in, v_in, pm_k, pm_v, lepe, outp);
}